// Round 11
// baseline (339.394 us; speedup 1.0000x reference)
//
#include <hip/hip_runtime.h>
#include <hip/hip_bf16.h>

#define B_ 4
#define N_ 4096
#define D_ 1024
#define H_ 16

typedef __attribute__((ext_vector_type(4))) float f32x4;
typedef __attribute__((ext_vector_type(8))) short s16x8;
typedef __attribute__((ext_vector_type(4))) unsigned int u32x4;

__device__ __forceinline__ ushort f2bf(float f) {
  union { float f; unsigned u; } v; v.f = f;
  unsigned u = v.u;
  return (ushort)((u + 0x7fffu + ((u >> 16) & 1u)) >> 16);
}

__device__ __forceinline__ void gld16(const ushort* g, ushort* lds_base) {
  __builtin_amdgcn_global_load_lds(
      (const __attribute__((address_space(1))) unsigned int*)g,
      (__attribute__((address_space(3))) unsigned int*)lds_base, 16, 0, 0);
}

__device__ __forceinline__ unsigned cvtpk(float lo, float hi) {
  unsigned r;
  asm("v_cvt_pk_bf16_f32 %0, %1, %2" : "=v"(r) : "v"(lo), "v"(hi));
  return r;
}

// ---------------- weight convert ----------------
__global__ void conv_w_kernel(const float* __restrict__ w0, const float* __restrict__ w1,
                              const float* __restrict__ w2, const float* __restrict__ w3,
                              ushort* __restrict__ dst) {
  const int z = blockIdx.z;
  const float* src = z == 0 ? w0 : z == 1 ? w1 : z == 2 ? w2 : w3;
  ushort* d = dst + (long)z * (D_ * D_);
  const long i0 = ((long)blockIdx.x * 256 + threadIdx.x) * 8;
  const long STR = (long)128 * 256 * 8;
#pragma unroll
  for (int u = 0; u < 4; ++u) {
    f32x4 a = *(const f32x4*)(src + i0 + u * STR);
    f32x4 b = *(const f32x4*)(src + i0 + u * STR + 4);
    s16x8 o;
    o[0] = (short)f2bf(a[0]); o[1] = (short)f2bf(a[1]); o[2] = (short)f2bf(a[2]); o[3] = (short)f2bf(a[3]);
    o[4] = (short)f2bf(b[0]); o[5] = (short)f2bf(b[1]); o[6] = (short)f2bf(b[2]); o[7] = (short)f2bf(b[3]);
    *(s16x8*)(d + i0 + u * STR) = o;
  }
}

// ---------------- gemm body: C[m,n] = sum_k A[m,k]*B[n,k], K=1024 ----------------
// BM=64, BN=256, BK=32, 256 thr = 4 waves (1M x 4N), per-wave out 64x64 (acc 4x4).
// r5-verbatim 2-phase schedule: sync -> stage -> sync -> MFMA (single buffer).
// Grid (M/64, 4): 4 n-sweeps of A instead of 8 -> L3 A-traffic halved.
// Swizzle (r8-verified, 0 conflicts): LDS[row][slot] = global col slot^((row>>1)&3).
// EPI: 0 = bf16 store (V), 1 = +bias head-softmax *1/8 (Q), 2 = exp + col partials (K),
//      3 = +bias fp32 store (final). Pointers pre-offset by wrapper.
template <int EPI, bool AFP32>
__device__ __forceinline__ void gemm_body(
    const void* __restrict__ Av, const ushort* __restrict__ Bm,
    void* __restrict__ Cv, const float* __restrict__ bias, float* __restrict__ kpart,
    int m0, int n0) {
  __shared__ ushort As[2048];  // [64][32]
  __shared__ ushort Bs[8192];  // [256][32]
  const int N = 1024;
  const int tid = threadIdx.x;
  const int lane = tid & 63;
  const int wn = tid >> 6;     // wave = n-block 0..3
  const int fl = lane & 15, fh = lane >> 4;
  f32x4 acc[4][4] = {};

  // B staging: 4 chunks/thread: c = tid + i*256, row = c>>2 (0..255), slot = c&3.
  // Dest linear (c*16B); source col inverse-swizzled.
  // A bf16 staging (EPI==3): 1 chunk: row = tid>>2 (0..63), slot = tid&3.
  const int br = tid >> 2;
  const int bsw = (((tid & 3) ^ ((br >> 1) & 3)) * 8);   // same (row>>1)&3 for row, row+64,...? no: per-chunk below
  const ushort* Ab = (const ushort*)Av;
  // per-chunk source pointers (row changes per chunk, so swizzle recomputed)
  const ushort* Asrc = AFP32 ? nullptr : (Ab + (long)(m0 + br) * 1024 + bsw);

  // A fp32 reg staging: row ar = tid>>2 (0..63), slot sl = tid&3 (8 floats);
  // 2 dwordx4 loads, 4 cvt_pk, 1 swizzled ds_write_b128.
  const int ar = tid >> 2, sl = tid & 3;
  const float* apA = AFP32 ? ((const float*)Av + (long)(m0 + ar) * 1024 + sl * 8) : nullptr;
  const int aw = ar * 32 + ((sl ^ ((ar >> 1) & 3)) * 8);

  // swizzled fragment-read: row = base16 + fl -> (row>>1)&3 == (fl>>1)&3
  const int fro = (fh ^ ((fl >> 1) & 3)) * 8;

  f32x4 qa0, qa1, qb0, qb1;

#define GLD_B(T) do { \
    _Pragma("unroll") for (int i = 0; i < 4; ++i) { \
      int c = tid + i * 256; \
      int row = c >> 2; \
      int sw = (((c & 3) ^ ((row >> 1) & 3)) * 8); \
      gld16(Bm + (long)(n0 + row) * 1024 + (T) * 32 + sw, Bs + c * 8); \
    } } while (0)
#define GLD_A16(T) do { gld16(Asrc + (T) * 32, As + tid * 8); } while (0)
#define ISSUE_P(T, S) do { \
    S##0 = *(const f32x4*)(apA + (T) * 32); \
    S##1 = *(const f32x4*)(apA + (T) * 32 + 4); } while (0)
#define CVT_WRITE(S) do { \
    u32x4 _w; \
    _w[0] = cvtpk(S##0[0], S##0[1]); _w[1] = cvtpk(S##0[2], S##0[3]); \
    _w[2] = cvtpk(S##1[0], S##1[1]); _w[3] = cvtpk(S##1[2], S##1[3]); \
    *(u32x4*)(As + aw) = _w; } while (0)
#define MFMA_STEP() do { \
    s16x8 fa[4], fb[4]; \
    _Pragma("unroll") for (int i = 0; i < 4; ++i) \
      fa[i] = *(const s16x8*)(As + (i * 16 + fl) * 32 + fro); \
    _Pragma("unroll") for (int j = 0; j < 4; ++j) \
      fb[j] = *(const s16x8*)(Bs + (wn * 64 + j * 16 + fl) * 32 + fro); \
    _Pragma("unroll") for (int i = 0; i < 4; ++i) \
      _Pragma("unroll") for (int j = 0; j < 4; ++j) \
        acc[i][j] = __builtin_amdgcn_mfma_f32_16x16x32_bf16(fa[i], fb[j], acc[i][j], 0, 0, 0); \
    } while (0)

  if constexpr (AFP32) {
    ISSUE_P(0, qa);
#pragma unroll 1
    for (int t = 0; t < 32; t += 2) {
      __syncthreads();
      GLD_B(t);
      CVT_WRITE(qa);           // waits only qa's 2 loads (B stays in flight)
      ISSUE_P(t + 1, qb);
      __syncthreads();
      MFMA_STEP();
      __syncthreads();
      GLD_B(t + 1);
      CVT_WRITE(qb);
      if (t + 2 < 32) ISSUE_P(t + 2, qa);
      __syncthreads();
      MFMA_STEP();
    }
  } else {
#pragma unroll 1
    for (int t = 0; t < 32; ++t) {
      __syncthreads();
      GLD_A16(t);
      GLD_B(t);
      __syncthreads();
      MFMA_STEP();
    }
  }
#undef GLD_B
#undef GLD_A16
#undef ISSUE_P
#undef CVT_WRITE
#undef MFMA_STEP

  // ---- epilogues: rows m0 + i*16 + fh*4 + r (i<4), cols n0 + wn*64 + j*16 + fl
  if constexpr (EPI == 0) {
    ushort* C = (ushort*)Cv;
#pragma unroll
    for (int j = 0; j < 4; ++j) {
      int col = n0 + wn * 64 + j * 16 + fl;
#pragma unroll
      for (int i = 0; i < 4; ++i)
#pragma unroll
        for (int r = 0; r < 4; ++r) {
          int row = m0 + i * 16 + fh * 4 + r;
          C[(long)row * N + col] = f2bf(acc[i][j][r]);
        }
    }
  } else if constexpr (EPI == 1) {
    // Q: +bias, softmax over the wave's 64-col head, scale 1/8
    ushort* C = (ushort*)Cv;
    float bcol[4];
#pragma unroll
    for (int j = 0; j < 4; ++j) bcol[j] = bias[n0 + wn * 64 + j * 16 + fl];
#pragma unroll
    for (int i = 0; i < 4; ++i)
#pragma unroll
      for (int r = 0; r < 4; ++r) {
        float v[4];
#pragma unroll
        for (int j = 0; j < 4; ++j) v[j] = acc[i][j][r] + bcol[j];
        float m = fmaxf(fmaxf(v[0], v[1]), fmaxf(v[2], v[3]));
#pragma unroll
        for (int o = 1; o <= 8; o <<= 1) m = fmaxf(m, __shfl_xor(m, o));
        float e[4], s = 0.f;
#pragma unroll
        for (int j = 0; j < 4; ++j) { e[j] = __expf(v[j] - m); s += e[j]; }
#pragma unroll
        for (int o = 1; o <= 8; o <<= 1) s += __shfl_xor(s, o);
        float sc = 0.125f / s;
        int row = m0 + i * 16 + fh * 4 + r;
#pragma unroll
        for (int j = 0; j < 4; ++j)
          C[(long)row * N + n0 + wn * 64 + j * 16 + fl] = f2bf(e[j] * sc);
      }
  } else if constexpr (EPI == 2) {
    // K: store exp(k); per-64-row-block column partial sums (deterministic)
    ushort* C = (ushort*)Cv;
    float csum[4] = {};
#pragma unroll
    for (int j = 0; j < 4; ++j) {
      int col = n0 + wn * 64 + j * 16 + fl;
#pragma unroll
      for (int i = 0; i < 4; ++i)
#pragma unroll
        for (int r = 0; r < 4; ++r) {
          int row = m0 + i * 16 + fh * 4 + r;
          float e = __expf(acc[i][j][r]);
          csum[j] += e;
          C[(long)row * N + col] = f2bf(e);
        }
    }
#pragma unroll
    for (int j = 0; j < 4; ++j) {
#pragma unroll
      for (int o = 16; o <= 32; o <<= 1) csum[j] += __shfl_xor(csum[j], o);
    }
    if (fh == 0) {
      int b = m0 >> 12;
      int chunk = (m0 & 4095) >> 6;  // 64 chunks of 64 rows per batch
#pragma unroll
      for (int j = 0; j < 4; ++j)
        kpart[(long)b * 65536 + (long)chunk * 1024 + n0 + wn * 64 + j * 16 + fl] = csum[j];
    }
  } else {
    float* C = (float*)Cv;
#pragma unroll
    for (int j = 0; j < 4; ++j) {
      int col = n0 + wn * 64 + j * 16 + fl;
      float bv = bias[col];
#pragma unroll
      for (int i = 0; i < 4; ++i)
#pragma unroll
        for (int r = 0; r < 4; ++r) {
          int row = m0 + i * 16 + fh * 4 + r;
          C[(long)row * N + col] = acc[i][j][r] + bv;
        }
    }
  }
}

// ---------------- named GEMM kernels ----------------
__global__ __launch_bounds__(256, 2) void gemm_q(const float* __restrict__ A,
                                                 const ushort* __restrict__ Bm,
                                                 ushort* __restrict__ C,
                                                 const float* __restrict__ bias) {
  gemm_body<1, true>(A, Bm, C, bias, nullptr, blockIdx.x * 64, blockIdx.y * 256);
}
__global__ __launch_bounds__(256, 2) void gemm_k(const float* __restrict__ A,
                                                 const ushort* __restrict__ Bm,
                                                 ushort* __restrict__ C,
                                                 float* __restrict__ kpart) {
  gemm_body<2, true>(A, Bm, C, nullptr, kpart, blockIdx.x * 64, blockIdx.y * 256);
}
__global__ __launch_bounds__(256, 2) void gemm_v(const float* __restrict__ A,
                                                 const ushort* __restrict__ Bm,
                                                 ushort* __restrict__ C) {
  gemm_body<0, true>(A, Bm, C, nullptr, nullptr, blockIdx.x * 64, blockIdx.y * 256);
}
__global__ __launch_bounds__(256, 2) void gemm_o(const ushort* __restrict__ A,
                                                 const ushort* __restrict__ Bm,
                                                 float* __restrict__ C,
                                                 const float* __restrict__ bias) {
  const int z = blockIdx.z;
  gemm_body<3, false>(A + (long)z * 4096 * 1024, Bm + (long)z * 1024 * 1024,
                      C + (long)z * 4096 * 1024, bias, nullptr,
                      blockIdx.x * 64, blockIdx.y * 256);
}

// ---------------- colinv[b][d] = 1 / sum_c kpart[b][c][d] ----------------
__global__ void ksm2_kernel(const float* __restrict__ kpart, float* __restrict__ colinv) {
  int idx = blockIdx.x * 256 + threadIdx.x;  // b*1024+d
  int b = idx >> 10, d = idx & 1023;
  float s = 0.f;
  for (int c = 0; c < 64; ++c) s += kpart[(long)b * 65536 + (long)c * 1024 + d];
  colinv[idx] = 1.0f / s;
}

// ---------------- ctx partial: part[chunk][bh][dk][e] = sum_{n in chunk(512)} expk[n,dk]*v[n,e] ----------------
__global__ __launch_bounds__(256, 2) void ctx_partial_kernel(
    const ushort* __restrict__ Ksm, const ushort* __restrict__ Vp, float* __restrict__ part) {
  __shared__ ushort Ks[128 * 64];
  __shared__ ushort Vs[128 * 64];
  const int chunk = blockIdx.x;  // 8 chunks of 512 rows
  const int bh = blockIdx.y;     // 64
  const int b = bh >> 4, h = bh & 15;
  const int tid = threadIdx.x, wave = tid >> 6, lane = tid & 63;
  const int fl = lane & 15, fh = lane >> 4;
  f32x4 acc[4] = {};
  for (int t = 0; t < 4; ++t) {
    const long base = ((long)(b * N_ + chunk * 512 + t * 128)) * D_ + h * 64;
    __syncthreads();
#pragma unroll
    for (int i = 0; i < 4; ++i) {
      int c = i * 256 + tid;
      int r = c >> 3, k8 = (c & 7) * 8;
      ushort* lk = Ks + (long)(i * 256 + wave * 64) * 8;
      ushort* lv = Vs + (long)(i * 256 + wave * 64) * 8;
      gld16(Ksm + base + (long)r * D_ + k8, lk);
      gld16(Vp + base + (long)r * D_ + k8, lv);
    }
    __syncthreads();
#pragma unroll
    for (int s = 0; s < 4; ++s) {
      s16x8 fa;
#pragma unroll
      for (int j = 0; j < 8; ++j)
        fa[j] = (short)Ks[(s * 32 + fh * 8 + j) * 64 + wave * 16 + fl];
#pragma unroll
      for (int jt = 0; jt < 4; ++jt) {
        s16x8 fb;
#pragma unroll
        for (int j = 0; j < 8; ++j)
          fb[j] = (short)Vs[(s * 32 + fh * 8 + j) * 64 + jt * 16 + fl];
        acc[jt] = __builtin_amdgcn_mfma_f32_16x16x32_bf16(fa, fb, acc[jt], 0, 0, 0);
      }
    }
  }
  float* dst = part + ((long)chunk * 64 + bh) * 4096;
#pragma unroll
  for (int jt = 0; jt < 4; ++jt)
#pragma unroll
    for (int r = 0; r < 4; ++r)
      dst[(wave * 16 + fh * 4 + r) * 64 + jt * 16 + fl] = acc[jt][r];
}

// ctxb[bh][dk][e] = bf16( colinv[b,h*64+dk] * sum_ch part + bv[h*64+e] )
__global__ void ctx_reduce_kernel(const float* __restrict__ part, const float* __restrict__ bv,
                                  const float* __restrict__ colinv, ushort* __restrict__ ctxb) {
  int idx = blockIdx.x * 256 + threadIdx.x;
  int e = idx & 63;
  int dk = (idx >> 6) & 63;
  int h = (idx >> 12) & 15;
  int b = idx >> 16;
  float s = 0.f;
#pragma unroll
  for (int c = 0; c < 8; ++c) s += part[(long)c * 262144 + idx];
  ctxb[idx] = f2bf(s * colinv[b * 1024 + h * 64 + dk] + bv[h * 64 + e]);
}

// Mb[b][o, h*64+dk] = sum_e Wo[o, h*64+e] * ctx[b,h][dk,e]
__global__ __launch_bounds__(256, 2) void mb_kernel(
    const ushort* __restrict__ Wob, const ushort* __restrict__ ctxb, ushort* __restrict__ Mb) {
  const int o0 = blockIdx.x * 64, h = blockIdx.y, b = blockIdx.z;
  const int tid = threadIdx.x, wave = tid >> 6, lane = tid & 63;
  const int fl = lane & 15, fh = lane >> 4;
  const ushort* ctxh = ctxb + ((long)(b * 16 + h)) * 4096;
  f32x4 acc[4] = {};
#pragma unroll
  for (int s = 0; s < 2; ++s) {
    s16x8 fa = *(const s16x8*)(Wob + (long)(o0 + wave * 16 + fl) * D_ + h * 64 + s * 32 + fh * 8);
#pragma unroll
    for (int jt = 0; jt < 4; ++jt) {
      s16x8 fb = *(const s16x8*)(ctxh + (long)(jt * 16 + fl) * 64 + s * 32 + fh * 8);
      acc[jt] = __builtin_amdgcn_mfma_f32_16x16x32_bf16(fa, fb, acc[jt], 0, 0, 0);
    }
  }
  ushort* dst = Mb + (long)b * (D_ * D_);
#pragma unroll
  for (int jt = 0; jt < 4; ++jt)
#pragma unroll
    for (int r = 0; r < 4; ++r)
      dst[(long)(o0 + wave * 16 + fh * 4 + r) * D_ + h * 64 + jt * 16 + fl] = f2bf(acc[jt][r]);
}

// ---------------- launch ----------------
extern "C" void kernel_launch(void* const* d_in, const int* in_sizes, int n_in,
                              void* d_out, int out_size, void* d_ws, size_t ws_size,
                              hipStream_t stream) {
  const float* q_in = (const float*)d_in[0];
  const float* k_in = (const float*)d_in[1];
  const float* v_in = (const float*)d_in[2];
  const float* Wq = (const float*)d_in[3];
  const float* bq = (const float*)d_in[4];
  const float* Wk = (const float*)d_in[5];
  const float* Wv = (const float*)d_in[7];
  const float* bv = (const float*)d_in[8];
  const float* Wo = (const float*)d_in[9];
  const float* bo = (const float*)d_in[10];

  char* ws = (char*)d_ws;
  ushort* Wb = (ushort*)(ws + 0);              // 8 MB
  ushort* Qp = (ushort*)(ws + 8388608);        // 32 MB
  ushort* Kp = (ushort*)(ws + 41943040);       // 32 MB
  ushort* Vp = (ushort*)(ws + 75497472);       // 32 MB
  float* kpart = (float*)(ws + 109051904);     // [4][64][1024] f32 = 1 MB
  float* colinv = (float*)(ws + 110100480);    // 16 KB
  float* ctxpart = (float*)(ws + 110116864);   // [8][64][4096] f32 = 8 MB
  ushort* ctxb = (ushort*)(ws + 118505472);    // 512 KB
  ushort* Mb = (ushort*)(ws + 119029760);      // 8 MB

  ushort* Wbq = Wb;
  ushort* Wbk = Wb + 1048576;
  ushort* Wbv = Wb + 2097152;
  ushort* Wbo = Wb + 3145728;

  conv_w_kernel<<<dim3(128, 1, 4), 256, 0, stream>>>(Wq, Wk, Wv, Wo, Wb);

  // projections: fp32 A read directly; M=16384 (256 m-tiles of 64), N=1024 (4 n-tiles of 256)
  gemm_q<<<dim3(256, 4), 256, 0, stream>>>(q_in, Wbq, Qp, bq);
  gemm_k<<<dim3(256, 4), 256, 0, stream>>>(k_in, Wbk, Kp, kpart);
  gemm_v<<<dim3(256, 4), 256, 0, stream>>>(v_in, Wbv, Vp);

  ksm2_kernel<<<16, 256, 0, stream>>>(kpart, colinv);

  ctx_partial_kernel<<<dim3(8, 64), 256, 0, stream>>>(Kp, Vp, ctxpart);
  ctx_reduce_kernel<<<1024, 256, 0, stream>>>(ctxpart, bv, colinv, ctxb);
  mb_kernel<<<dim3(16, 16, 4), 256, 0, stream>>>(Wbo, ctxb, Mb);

  // final: per-batch out = Qp_b @ Mb_b^T + bo (fp32 out); 64 m-tiles x 4 n-tiles x 4 z
  gemm_o<<<dim3(64, 4, 4), 256, 0, stream>>>(Qp, Mb, (float*)d_out, bo);
}

// Round 12
// 301.771 us; speedup vs baseline: 1.1247x; 1.1247x over previous
//
#include <hip/hip_runtime.h>
#include <hip/hip_bf16.h>

#define B_ 4
#define N_ 4096
#define D_ 1024
#define H_ 16

typedef __attribute__((ext_vector_type(4))) float f32x4;
typedef __attribute__((ext_vector_type(8))) short s16x8;
typedef __attribute__((ext_vector_type(4))) unsigned int u32x4;

__device__ __forceinline__ ushort f2bf(float f) {
  union { float f; unsigned u; } v; v.f = f;
  unsigned u = v.u;
  return (ushort)((u + 0x7fffu + ((u >> 16) & 1u)) >> 16);
}

__device__ __forceinline__ void gld16(const ushort* g, ushort* lds_base) {
  __builtin_amdgcn_global_load_lds(
      (const __attribute__((address_space(1))) unsigned int*)g,
      (__attribute__((address_space(3))) unsigned int*)lds_base, 16, 0, 0);
}

__device__ __forceinline__ unsigned cvtpk(float lo, float hi) {
  unsigned r;
  asm("v_cvt_pk_bf16_f32 %0, %1, %2" : "=v"(r) : "v"(lo), "v"(hi));
  return r;
}

// ---------------- weight convert ----------------
__global__ void conv_w_kernel(const float* __restrict__ w0, const float* __restrict__ w1,
                              const float* __restrict__ w2, const float* __restrict__ w3,
                              ushort* __restrict__ dst) {
  const int z = blockIdx.z;
  const float* src = z == 0 ? w0 : z == 1 ? w1 : z == 2 ? w2 : w3;
  ushort* d = dst + (long)z * (D_ * D_);
  const long i0 = ((long)blockIdx.x * 256 + threadIdx.x) * 8;
  const long STR = (long)128 * 256 * 8;
#pragma unroll
  for (int u = 0; u < 4; ++u) {
    f32x4 a = *(const f32x4*)(src + i0 + u * STR);
    f32x4 b = *(const f32x4*)(src + i0 + u * STR + 4);
    s16x8 o;
    o[0] = (short)f2bf(a[0]); o[1] = (short)f2bf(a[1]); o[2] = (short)f2bf(a[2]); o[3] = (short)f2bf(a[3]);
    o[4] = (short)f2bf(b[0]); o[5] = (short)f2bf(b[1]); o[6] = (short)f2bf(b[2]); o[7] = (short)f2bf(b[3]);
    *(s16x8*)(d + i0 + u * STR) = o;
  }
}

// ================= merged projection GEMM =================
// r5-exact structure: 128x128 tile, BK=32, 256 thr = 4 waves (2Mx2N), acc 4x4/wave,
// single-buffer 16 KB LDS, plain __syncthreads 2-phase loop.
// Added (r10-verified, 0-conflict): XOR swizzle — LDS[row][slot] holds global col
// slot^((row>>1)&3); B staged via pre-swizzled gld16 source, A (fp32 reg path) via
// swizzled ds_write_b128, reads XOR with ((fl>>1)&3).
// grid = (128 m-tiles, 8 n-tiles, 3): z = 0 Q (bias+head-softmax/8), 1 K (exp +
// col-partials), 2 V (plain bf16).
__global__ __launch_bounds__(256, 2) void gemm_qkv(
    const float* __restrict__ q_in, const float* __restrict__ k_in,
    const float* __restrict__ v_in, const ushort* __restrict__ Wb,
    ushort* __restrict__ P, const float* __restrict__ bq, float* __restrict__ kpart) {
  __shared__ ushort As[4096];  // [128][32]
  __shared__ ushort Bs[4096];
  const int z = blockIdx.z;
  const float* Af = z == 0 ? q_in : (z == 1 ? k_in : v_in);
  const ushort* Bm = Wb + (long)z * 1048576;
  ushort* C = P + (long)z * 16777216;
  const int m0 = blockIdx.x * 128, n0 = blockIdx.y * 128;
  const int N = 1024;
  const int tid = threadIdx.x;
  const int lane = tid & 63, wave = tid >> 6;
  const int fl = lane & 15, fh = lane >> 4;
  const int wm = wave >> 1, wn = wave & 1;
  f32x4 acc[4][4] = {};

  // B staging: chunks c0 = tid (rows 0..63), c1 = tid+256 (rows 64..127); slot = tid&3.
  // Source col pre-swizzled; dest linear. (row+64 has same (row>>1)&3.)
  const int r0 = tid >> 2;
  const int s8 = (((tid & 3) ^ ((r0 >> 1) & 3)) * 8);
  const ushort* Bsrc0 = Bm + (long)(n0 + r0) * 1024 + s8;
  const ushort* Bsrc1 = Bm + (long)(n0 + r0 + 64) * 1024 + s8;

  // A fp32 reg staging: row ar = tid>>1 (0..127), 16 floats at ch*16;
  // 2 swizzled ds_write_b128 at slots ch*2, ch*2+1.
  const int ar = tid >> 1, ch = tid & 1;
  const float* apA = Af + (long)(m0 + ar) * 1024 + ch * 16;
  const int aw0 = ar * 32 + (((ch * 2) ^ ((ar >> 1) & 3)) * 8);
  const int aw1 = ar * 32 + (((ch * 2 + 1) ^ ((ar >> 1) & 3)) * 8);

  // swizzled fragment read offset
  const int fro = (fh ^ ((fl >> 1) & 3)) * 8;

  f32x4 pa0, pa1, pa2, pa3;
  pa0 = *(const f32x4*)(apA);
  pa1 = *(const f32x4*)(apA + 4);
  pa2 = *(const f32x4*)(apA + 8);
  pa3 = *(const f32x4*)(apA + 12);

  for (int kk = 0; kk < 1024; kk += 32) {
    __syncthreads();
    gld16(Bsrc0 + kk, Bs + tid * 8);
    gld16(Bsrc1 + kk, Bs + 2048 + tid * 8);
    {
      u32x4 w0, w1;
      w0[0] = cvtpk(pa0[0], pa0[1]); w0[1] = cvtpk(pa0[2], pa0[3]);
      w0[2] = cvtpk(pa1[0], pa1[1]); w0[3] = cvtpk(pa1[2], pa1[3]);
      w1[0] = cvtpk(pa2[0], pa2[1]); w1[1] = cvtpk(pa2[2], pa2[3]);
      w1[2] = cvtpk(pa3[0], pa3[1]); w1[3] = cvtpk(pa3[2], pa3[3]);
      *(u32x4*)(As + aw0) = w0;
      *(u32x4*)(As + aw1) = w1;
      if (kk + 32 < 1024) {
        pa0 = *(const f32x4*)(apA + kk + 32);
        pa1 = *(const f32x4*)(apA + kk + 36);
        pa2 = *(const f32x4*)(apA + kk + 40);
        pa3 = *(const f32x4*)(apA + kk + 44);
      }
    }
    __syncthreads();
    s16x8 fa[4], fb[4];
#pragma unroll
    for (int i = 0; i < 4; ++i)
      fa[i] = *(const s16x8*)(As + (wm * 64 + i * 16 + fl) * 32 + fro);
#pragma unroll
    for (int j = 0; j < 4; ++j)
      fb[j] = *(const s16x8*)(Bs + (wn * 64 + j * 16 + fl) * 32 + fro);
#pragma unroll
    for (int i = 0; i < 4; ++i)
#pragma unroll
      for (int j = 0; j < 4; ++j)
        acc[i][j] = __builtin_amdgcn_mfma_f32_16x16x32_bf16(fa[i], fb[j], acc[i][j], 0, 0, 0);
  }

  if (z == 0) {
    // Q: +bias, softmax over the wave's 64-col head, scale 1/8
    float bcol[4];
#pragma unroll
    for (int j = 0; j < 4; ++j) bcol[j] = bq[n0 + wn * 64 + j * 16 + fl];
#pragma unroll
    for (int i = 0; i < 4; ++i)
#pragma unroll
      for (int r = 0; r < 4; ++r) {
        float v[4];
#pragma unroll
        for (int j = 0; j < 4; ++j) v[j] = acc[i][j][r] + bcol[j];
        float m = fmaxf(fmaxf(v[0], v[1]), fmaxf(v[2], v[3]));
#pragma unroll
        for (int o = 1; o <= 8; o <<= 1) m = fmaxf(m, __shfl_xor(m, o));
        float e[4], s = 0.f;
#pragma unroll
        for (int j = 0; j < 4; ++j) { e[j] = __expf(v[j] - m); s += e[j]; }
#pragma unroll
        for (int o = 1; o <= 8; o <<= 1) s += __shfl_xor(s, o);
        float sc = 0.125f / s;
        int row = m0 + wm * 64 + i * 16 + fh * 4 + r;
#pragma unroll
        for (int j = 0; j < 4; ++j)
          C[(long)row * N + n0 + wn * 64 + j * 16 + fl] = f2bf(e[j] * sc);
      }
  } else if (z == 1) {
    // K: store exp(k); per-64-row-block column partial sums (deterministic)
    float csum[4] = {};
#pragma unroll
    for (int j = 0; j < 4; ++j) {
      int col = n0 + wn * 64 + j * 16 + fl;
#pragma unroll
      for (int i = 0; i < 4; ++i)
#pragma unroll
        for (int r = 0; r < 4; ++r) {
          int row = m0 + wm * 64 + i * 16 + fh * 4 + r;
          float e = __expf(acc[i][j][r]);
          csum[j] += e;
          C[(long)row * N + col] = f2bf(e);
        }
    }
#pragma unroll
    for (int j = 0; j < 4; ++j) {
#pragma unroll
      for (int o = 16; o <= 32; o <<= 1) csum[j] += __shfl_xor(csum[j], o);
    }
    if (fh == 0) {
      int b = m0 >> 12;
      int chunk = ((m0 & 4095) >> 7) * 2 + wm;  // 64 chunks of 64 rows per batch
#pragma unroll
      for (int j = 0; j < 4; ++j)
        kpart[(long)b * 65536 + (long)chunk * 1024 + n0 + wn * 64 + j * 16 + fl] = csum[j];
    }
  } else {
    // V: plain bf16 store
#pragma unroll
    for (int j = 0; j < 4; ++j) {
      int col = n0 + wn * 64 + j * 16 + fl;
#pragma unroll
      for (int i = 0; i < 4; ++i)
#pragma unroll
        for (int r = 0; r < 4; ++r) {
          int row = m0 + wm * 64 + i * 16 + fh * 4 + r;
          C[(long)row * N + col] = f2bf(acc[i][j][r]);
        }
    }
  }
}

// ================= final GEMM (bf16 A, r5 structure + swizzle) =================
__global__ __launch_bounds__(256, 2) void gemm_o(const ushort* __restrict__ Ain,
                                                 const ushort* __restrict__ Bin,
                                                 float* __restrict__ Cout,
                                                 const float* __restrict__ bias) {
  __shared__ ushort As[4096];
  __shared__ ushort Bs[4096];
  const int z = blockIdx.z;
  const ushort* Ab = Ain + (long)z * 4096 * 1024;
  const ushort* Bm = Bin + (long)z * 1024 * 1024;
  float* C = Cout + (long)z * 4096 * 1024;
  const int m0 = blockIdx.x * 128, n0 = blockIdx.y * 128;
  const int N = 1024;
  const int tid = threadIdx.x;
  const int lane = tid & 63, wave = tid >> 6;
  const int fl = lane & 15, fh = lane >> 4;
  const int wm = wave >> 1, wn = wave & 1;
  f32x4 acc[4][4] = {};

  const int r0 = tid >> 2;
  const int s8 = (((tid & 3) ^ ((r0 >> 1) & 3)) * 8);
  const ushort* Bsrc0 = Bm + (long)(n0 + r0) * 1024 + s8;
  const ushort* Bsrc1 = Bm + (long)(n0 + r0 + 64) * 1024 + s8;
  const ushort* Asrc0 = Ab + (long)(m0 + r0) * 1024 + s8;
  const ushort* Asrc1 = Ab + (long)(m0 + r0 + 64) * 1024 + s8;
  const int fro = (fh ^ ((fl >> 1) & 3)) * 8;

  for (int kk = 0; kk < 1024; kk += 32) {
    __syncthreads();
    gld16(Asrc0 + kk, As + tid * 8);
    gld16(Asrc1 + kk, As + 2048 + tid * 8);
    gld16(Bsrc0 + kk, Bs + tid * 8);
    gld16(Bsrc1 + kk, Bs + 2048 + tid * 8);
    __syncthreads();
    s16x8 fa[4], fb[4];
#pragma unroll
    for (int i = 0; i < 4; ++i)
      fa[i] = *(const s16x8*)(As + (wm * 64 + i * 16 + fl) * 32 + fro);
#pragma unroll
    for (int j = 0; j < 4; ++j)
      fb[j] = *(const s16x8*)(Bs + (wn * 64 + j * 16 + fl) * 32 + fro);
#pragma unroll
    for (int i = 0; i < 4; ++i)
#pragma unroll
      for (int j = 0; j < 4; ++j)
        acc[i][j] = __builtin_amdgcn_mfma_f32_16x16x32_bf16(fa[i], fb[j], acc[i][j], 0, 0, 0);
  }

#pragma unroll
  for (int j = 0; j < 4; ++j) {
    int col = n0 + wn * 64 + j * 16 + fl;
    float bv = bias[col];
#pragma unroll
    for (int i = 0; i < 4; ++i)
#pragma unroll
      for (int r = 0; r < 4; ++r) {
        int row = m0 + wm * 64 + i * 16 + fh * 4 + r;
        C[(long)row * N + col] = acc[i][j][r] + bv;
      }
  }
}

// ---------------- colinv[b][d] = 1 / sum_c kpart[b][c][d] ----------------
__global__ void ksm2_kernel(const float* __restrict__ kpart, float* __restrict__ colinv) {
  int idx = blockIdx.x * 256 + threadIdx.x;  // b*1024+d
  int b = idx >> 10, d = idx & 1023;
  float s = 0.f;
  for (int c = 0; c < 64; ++c) s += kpart[(long)b * 65536 + (long)c * 1024 + d];
  colinv[idx] = 1.0f / s;
}

// ---------------- ctx partial ----------------
__global__ __launch_bounds__(256, 2) void ctx_partial_kernel(
    const ushort* __restrict__ Ksm, const ushort* __restrict__ Vp, float* __restrict__ part) {
  __shared__ ushort Ks[128 * 64];
  __shared__ ushort Vs[128 * 64];
  const int chunk = blockIdx.x;  // 8 chunks of 512 rows
  const int bh = blockIdx.y;     // 64
  const int b = bh >> 4, h = bh & 15;
  const int tid = threadIdx.x, wave = tid >> 6, lane = tid & 63;
  const int fl = lane & 15, fh = lane >> 4;
  f32x4 acc[4] = {};
  for (int t = 0; t < 4; ++t) {
    const long base = ((long)(b * N_ + chunk * 512 + t * 128)) * D_ + h * 64;
    __syncthreads();
#pragma unroll
    for (int i = 0; i < 4; ++i) {
      int c = i * 256 + tid;
      int r = c >> 3, k8 = (c & 7) * 8;
      ushort* lk = Ks + (long)(i * 256 + wave * 64) * 8;
      ushort* lv = Vs + (long)(i * 256 + wave * 64) * 8;
      gld16(Ksm + base + (long)r * D_ + k8, lk);
      gld16(Vp + base + (long)r * D_ + k8, lv);
    }
    __syncthreads();
#pragma unroll
    for (int s = 0; s < 4; ++s) {
      s16x8 fa;
#pragma unroll
      for (int j = 0; j < 8; ++j)
        fa[j] = (short)Ks[(s * 32 + fh * 8 + j) * 64 + wave * 16 + fl];
#pragma unroll
      for (int jt = 0; jt < 4; ++jt) {
        s16x8 fb;
#pragma unroll
        for (int j = 0; j < 8; ++j)
          fb[j] = (short)Vs[(s * 32 + fh * 8 + j) * 64 + jt * 16 + fl];
        acc[jt] = __builtin_amdgcn_mfma_f32_16x16x32_bf16(fa, fb, acc[jt], 0, 0, 0);
      }
    }
  }
  float* dst = part + ((long)chunk * 64 + bh) * 4096;
#pragma unroll
  for (int jt = 0; jt < 4; ++jt)
#pragma unroll
    for (int r = 0; r < 4; ++r)
      dst[(wave * 16 + fh * 4 + r) * 64 + jt * 16 + fl] = acc[jt][r];
}

// ctxb[bh][dk][e] = bf16( colinv[b,h*64+dk] * sum_ch part + bv[h*64+e] )
__global__ void ctx_reduce_kernel(const float* __restrict__ part, const float* __restrict__ bv,
                                  const float* __restrict__ colinv, ushort* __restrict__ ctxb) {
  int idx = blockIdx.x * 256 + threadIdx.x;
  int e = idx & 63;
  int dk = (idx >> 6) & 63;
  int h = (idx >> 12) & 15;
  int b = idx >> 16;
  float s = 0.f;
#pragma unroll
  for (int c = 0; c < 8; ++c) s += part[(long)c * 262144 + idx];
  ctxb[idx] = f2bf(s * colinv[b * 1024 + h * 64 + dk] + bv[h * 64 + e]);
}

// Mb[b][o, h*64+dk] = sum_e Wo[o, h*64+e] * ctx[b,h][dk,e]
__global__ __launch_bounds__(256, 2) void mb_kernel(
    const ushort* __restrict__ Wob, const ushort* __restrict__ ctxb, ushort* __restrict__ Mb) {
  const int o0 = blockIdx.x * 64, h = blockIdx.y, b = blockIdx.z;
  const int tid = threadIdx.x, wave = tid >> 6, lane = tid & 63;
  const int fl = lane & 15, fh = lane >> 4;
  const ushort* ctxh = ctxb + ((long)(b * 16 + h)) * 4096;
  f32x4 acc[4] = {};
#pragma unroll
  for (int s = 0; s < 2; ++s) {
    s16x8 fa = *(const s16x8*)(Wob + (long)(o0 + wave * 16 + fl) * D_ + h * 64 + s * 32 + fh * 8);
#pragma unroll
    for (int jt = 0; jt < 4; ++jt) {
      s16x8 fb = *(const s16x8*)(ctxh + (long)(jt * 16 + fl) * 64 + s * 32 + fh * 8);
      acc[jt] = __builtin_amdgcn_mfma_f32_16x16x32_bf16(fa, fb, acc[jt], 0, 0, 0);
    }
  }
  ushort* dst = Mb + (long)b * (D_ * D_);
#pragma unroll
  for (int jt = 0; jt < 4; ++jt)
#pragma unroll
    for (int r = 0; r < 4; ++r)
      dst[(long)(o0 + wave * 16 + fh * 4 + r) * D_ + h * 64 + jt * 16 + fl] = f2bf(acc[jt][r]);
}

// ---------------- launch ----------------
extern "C" void kernel_launch(void* const* d_in, const int* in_sizes, int n_in,
                              void* d_out, int out_size, void* d_ws, size_t ws_size,
                              hipStream_t stream) {
  const float* q_in = (const float*)d_in[0];
  const float* k_in = (const float*)d_in[1];
  const float* v_in = (const float*)d_in[2];
  const float* Wq = (const float*)d_in[3];
  const float* bq = (const float*)d_in[4];
  const float* Wk = (const float*)d_in[5];
  const float* Wv = (const float*)d_in[7];
  const float* bv = (const float*)d_in[8];
  const float* Wo = (const float*)d_in[9];
  const float* bo = (const float*)d_in[10];

  char* ws = (char*)d_ws;
  ushort* Wb = (ushort*)(ws + 0);              // 8 MB
  ushort* Qp = (ushort*)(ws + 8388608);        // Qp/Kp/Vp contiguous, 32 MB apart
  float* kpart = (float*)(ws + 109051904);     // [4][64][1024] f32 = 1 MB
  float* colinv = (float*)(ws + 110100480);    // 16 KB
  float* ctxpart = (float*)(ws + 110116864);   // [8][64][4096] f32 = 8 MB
  ushort* ctxb = (ushort*)(ws + 118505472);    // 512 KB
  ushort* Mb = (ushort*)(ws + 119029760);      // 8 MB

  ushort* Kp = Qp + 16777216;
  ushort* Vp = Qp + 33554432;
  ushort* Wbo = Wb + 3145728;

  conv_w_kernel<<<dim3(128, 1, 4), 256, 0, stream>>>(Wq, Wk, Wv, Wo, Wb);

  // merged projections: z = 0 (Q), 1 (K), 2 (V)
  gemm_qkv<<<dim3(128, 8, 3), 256, 0, stream>>>(q_in, k_in, v_in, Wb, Qp, bq, kpart);

  ksm2_kernel<<<16, 256, 0, stream>>>(kpart, colinv);

  ctx_partial_kernel<<<dim3(8, 64), 256, 0, stream>>>(Kp, Vp, ctxpart);
  ctx_reduce_kernel<<<1024, 256, 0, stream>>>(ctxpart, bv, colinv, ctxb);
  mb_kernel<<<dim3(16, 16, 4), 256, 0, stream>>>(Wbo, ctxb, Mb);

  // final: per-batch out = Qp_b @ Mb_b^T + bo (fp32 out)
  gemm_o<<<dim3(32, 8, 4), 256, 0, stream>>>(Qp, Mb, (float*)d_out, bo);
}